// Round 5
// baseline (235.399 us; speedup 1.0000x reference)
//
#include <hip/hip_runtime.h>
#include <hip/hip_bf16.h>
#include <stdint.h>

// Problem: B=8, L=1024, C=1024, H=16, HD=64, window +/-64 (WS=128).
// Round-14: OBSERVABILITY round. Four rounds of top-5 tables showed only
// gemm_qkv (5 instances x ~68us) — attn/proj never surfaced, and blind
// theories about them were falsified (r13 proj tile: predicted -30us, got
// +4us -> proj NOT occupancy-bound; reverted to 128x128).
// This round: split gemm_qkv into two half-N dispatches (~34us each, grid
// (12,64), disjoint W halves) so attn_local / gemm_proj surface in top-5
// with full counters. Everything else = round-3 best-known config.

typedef __attribute__((ext_vector_type(8))) short bf16x8;
typedef __attribute__((ext_vector_type(4))) float f32x4;

__device__ inline unsigned short f2b(float f) {
    __hip_bfloat16 h = __float2bfloat16(f);
    return *reinterpret_cast<unsigned short*>(&h);
}

// async global->LDS, 16B per lane; LDS dest = wave-uniform base + lane*16
__device__ inline void gld16(const unsigned short* g, unsigned short* l) {
    __builtin_amdgcn_global_load_lds(
        (const __attribute__((address_space(1))) void*)g,
        (__attribute__((address_space(3))) void*)l, 16, 0, 0);
}

#define BM 128
#define BN 128
#define BK 64

// ---- cast f32 inputs to bf16 side buffers: 8 f32 -> one 16B store ----
__global__ void __launch_bounds__(256) cast_inputs(
    const float4* __restrict__ x, const float4* __restrict__ w1,
    const float4* __restrict__ w2,
    uint4* __restrict__ xb, uint4* __restrict__ w1b, uint4* __restrict__ w2b)
{
    const int P0 = 1048576, P1 = 393216, P2 = 131072;  // float4-pair counts
    int stride = gridDim.x * blockDim.x;
    for (int i = blockIdx.x * blockDim.x + threadIdx.x; i < P0 + P1 + P2; i += stride) {
        const float4* src; uint4* dst; int idx;
        if (i < P0)           { src = x;  dst = xb;  idx = i; }
        else if (i < P0 + P1) { src = w1; dst = w1b; idx = i - P0; }
        else                  { src = w2; dst = w2b; idx = i - P0 - P1; }
        float4 a = src[idx * 2], b = src[idx * 2 + 1];
        unsigned short t[8] = {f2b(a.x), f2b(a.y), f2b(a.z), f2b(a.w),
                               f2b(b.x), f2b(b.y), f2b(b.z), f2b(b.w)};
        dst[idx] = *(uint4*)t;
    }
}

// ---- QKV GEMM: C[M,N] = xb[M,K] * w1b[N,K]^T + b1 ; scatter to Q/K/V ----
// 128x64 LDS tiles, XOR swizzle (chunk c of row r at c^(r&7)); DMA staging.
// Round-14: n_base param -> launched as two half-N dispatches for top-5
// observability (each 768 blocks = 3 exact rounds/CU).
__global__ void __launch_bounds__(256) gemm_qkv(
    const unsigned short* __restrict__ A,   // xb [8192,1024] bf16
    const unsigned short* __restrict__ W,   // w1b [3072,1024] bf16
    const float* __restrict__ bias,         // [3072] f32
    unsigned short* __restrict__ Qo,
    unsigned short* __restrict__ Ko,
    unsigned short* __restrict__ Vo,
    int n_base)
{
    const int K = 1024;
    int n0 = n_base + blockIdx.x * BN;
    int m0 = blockIdx.y * BM;
    int tid = threadIdx.x;
    int wave = tid >> 6, lane = tid & 63;
    int lm = lane & 15, quad = lane >> 4;
    int mblk = (wave & 1) * 64, nblk = (wave >> 1) * 64;

    __shared__ unsigned short As[BM * BK];  // 16 KiB
    __shared__ unsigned short Bs[BN * BK];  // 16 KiB

    int drow = lane >> 3;               // 0..7 row within an 8-row DMA chunk
    int gcc  = (lane & 7) ^ drow;       // swizzled logical col-chunk (x8 elems)
    const unsigned short* ga[4]; const unsigned short* gb[4];
    unsigned short *la[4], *lb[4];
#pragma unroll
    for (int p = 0; p < 4; ++p) {
        int r = wave * 32 + p * 8 + drow;
        ga[p] = A + (size_t)(m0 + r) * K + gcc * 8;
        gb[p] = W + (size_t)(n0 + r) * K + gcc * 8;
        la[p] = As + (wave * 32 + p * 8) * 64;
        lb[p] = Bs + (wave * 32 + p * 8) * 64;
    }
    int lm7 = lm & 7;

    f32x4 acc[4][4];
#pragma unroll
    for (int i = 0; i < 4; ++i)
#pragma unroll
        for (int j = 0; j < 4; ++j)
            acc[i][j] = (f32x4){0.f, 0.f, 0.f, 0.f};

    for (int k0 = 0; k0 < K; k0 += BK) {
        __syncthreads();                 // prev iter's ds_reads done
#pragma unroll
        for (int p = 0; p < 4; ++p) gld16(ga[p] + k0, la[p]);
#pragma unroll
        for (int p = 0; p < 4; ++p) gld16(gb[p] + k0, lb[p]);
        __syncthreads();                 // DMA drained
        bf16x8 af[4][2], bfr[4][2];
#pragma unroll
        for (int i = 0; i < 4; ++i)
#pragma unroll
            for (int hhh = 0; hhh < 2; ++hhh)
                af[i][hhh] = *(const bf16x8*)(As + (mblk + i * 16 + lm) * 64 +
                                              (((hhh * 4 + quad) ^ lm7) << 3));
#pragma unroll
        for (int j = 0; j < 4; ++j)
#pragma unroll
            for (int hhh = 0; hhh < 2; ++hhh)
                bfr[j][hhh] = *(const bf16x8*)(Bs + (nblk + j * 16 + lm) * 64 +
                                               (((hhh * 4 + quad) ^ lm7) << 3));
#pragma unroll
        for (int i = 0; i < 4; ++i)
#pragma unroll
            for (int j = 0; j < 4; ++j) {
                acc[i][j] = __builtin_amdgcn_mfma_f32_16x16x32_bf16(af[i][0], bfr[j][0], acc[i][j], 0, 0, 0);
                acc[i][j] = __builtin_amdgcn_mfma_f32_16x16x32_bf16(af[i][1], bfr[j][1], acc[i][j], 0, 0, 0);
            }
    }

#pragma unroll
    for (int j = 0; j < 4; ++j) {
        int n = n0 + nblk + j * 16 + lm;
        float bv = bias[n];
        int sec = n >> 10, rem = n & 1023;
        int h = rem >> 6, d = rem & 63;
        unsigned short* dst = (sec == 0) ? Qo : (sec == 1) ? Ko : Vo;
#pragma unroll
        for (int i = 0; i < 4; ++i) {
#pragma unroll
            for (int r = 0; r < 4; ++r) {
                int m = m0 + mblk + i * 16 + quad * 4 + r;
                int bb = m >> 10, sl = m & 1023;
                size_t idx = ((size_t)((bb * 16 + h) * 1024 + sl)) * 64 + d;
                dst[idx] = f2b(acc[i][j][r] + bv);
            }
        }
    }
}

// ---- local attention (byte-identical to round-3 version) ----
// One block per (b,h,64-row q tile). Keys window [q0-64, q0+128) = 192.
// Wave w (q rows [q0+16w,+16)) computes only key tiles [w, w+8] (9 of 12)
// and 5 of 6 PV chunks; the one uncovered tile is zeroed in P.
__global__ void __launch_bounds__(256) attn_local(
    const unsigned short* __restrict__ Qg,   // [B*H,1024,64] bf16
    const unsigned short* __restrict__ Kg,   // [B*H,1024,64] bf16
    const unsigned short* __restrict__ Vg,   // [B*H,1024,64] bf16
    unsigned short* __restrict__ Og)         // [8192,1024] bf16
{
    const int KP = 72;    // K-tile pitch (64+8)
    const int VP = 200;   // Vt / P pitch (192+8)
    __shared__ unsigned short Ks[192 * KP];  // reused as P after barrier
    __shared__ unsigned short Vt[64 * VP];

    int tid = threadIdx.x;
    int wave = tid >> 6, lane = tid & 63;
    int lm = lane & 15, quad = lane >> 4;

    int bh = blockIdx.x >> 4;
    int qt = blockIdx.x & 15;
    int q0 = qt * 64;
    int b = bh >> 4, h = bh & 15;
    const unsigned short* Qbh = Qg + (size_t)bh * 1024 * 64;
    const unsigned short* Kbh = Kg + (size_t)bh * 1024 * 64;
    const unsigned short* Vbh = Vg + (size_t)bh * 1024 * 64;
    int j0 = q0 - 64;

    // stage K rows + V^T (write order staggered by tid&7)
    int k7 = tid & 7;
#pragma unroll
    for (int it = 0; it < 6; ++it) {
        int id = it * 256 + tid;
        int r = id >> 3;             // key row 0..191
        int c = (id & 7) * 8;        // d offset
        int j = j0 + r;
        uint4 kv, vv;
        kv.x = kv.y = kv.z = kv.w = 0;
        vv = kv;
        if (j >= 0 && j < 1024) {
            kv = *(const uint4*)(Kbh + (size_t)j * 64 + c);
            vv = *(const uint4*)(Vbh + (size_t)j * 64 + c);
        }
        *(uint4*)(Ks + r * KP + c) = kv;
        unsigned short tmp[8];
        *(uint4*)tmp = vv;
#pragma unroll
        for (int e0 = 0; e0 < 8; ++e0) {
            int e = (e0 + k7) & 7;
            Vt[(c + e) * VP + r] = tmp[e];
        }
    }
    __syncthreads();

    int qrow = q0 + wave * 16;
    bf16x8 qf0 = *(const bf16x8*)(Qbh + (size_t)(qrow + lm) * 64 + quad * 8);
    bf16x8 qf1 = *(const bf16x8*)(Qbh + (size_t)(qrow + lm) * 64 + 32 + quad * 8);

    // scores: 9 key tiles [wave, wave+8]
    f32x4 sc[9];
#pragma unroll
    for (int kt = 0; kt < 9; ++kt) {
        int akt = wave + kt;
        f32x4 a = (f32x4){0.f, 0.f, 0.f, 0.f};
        bf16x8 k0f = *(const bf16x8*)(Ks + (akt * 16 + lm) * KP + quad * 8);
        bf16x8 k1f = *(const bf16x8*)(Ks + (akt * 16 + lm) * KP + 32 + quad * 8);
        a = __builtin_amdgcn_mfma_f32_16x16x32_bf16(qf0, k0f, a, 0, 0, 0);
        a = __builtin_amdgcn_mfma_f32_16x16x32_bf16(qf1, k1f, a, 0, 0, 0);
        sc[kt] = a;
    }

    float mx[4] = {-3e38f, -3e38f, -3e38f, -3e38f};
#pragma unroll
    for (int kt = 0; kt < 9; ++kt) {
        int jg = j0 + (wave + kt) * 16 + lm;
#pragma unroll
        for (int r = 0; r < 4; ++r) {
            int irow = q0 + wave * 16 + quad * 4 + r;
            int diff = irow - jg;
            bool ok = (jg >= 0) && (jg < 1024) && (diff <= 64) && (diff >= -64);
            float s = ok ? sc[kt][r] * 0.125f : -30000.0f;
            sc[kt][r] = s;
            mx[r] = fmaxf(mx[r], s);
        }
    }
#pragma unroll
    for (int off = 1; off <= 8; off <<= 1)
#pragma unroll
        for (int r = 0; r < 4; ++r)
            mx[r] = fmaxf(mx[r], __shfl_xor(mx[r], off, 64));

    float sum[4] = {0.f, 0.f, 0.f, 0.f};
#pragma unroll
    for (int kt = 0; kt < 9; ++kt)
#pragma unroll
        for (int r = 0; r < 4; ++r) {
            float p = __expf(sc[kt][r] - mx[r]);
            sc[kt][r] = p;
            sum[r] += p;
        }
#pragma unroll
    for (int off = 1; off <= 8; off <<= 1)
#pragma unroll
        for (int r = 0; r < 4; ++r)
            sum[r] += __shfl_xor(sum[r], off, 64);

    __syncthreads();  // done reading Ks as K tile
    unsigned short* Pb = Ks + wave * 3200;  // per-wave P [16][VP]
#pragma unroll
    for (int kt = 0; kt < 9; ++kt) {
        int akt = wave + kt;
#pragma unroll
        for (int r0 = 0; r0 < 4; ++r0) {
            int r = (r0 + quad) & 3;
            Pb[(quad * 4 + r) * VP + akt * 16 + lm] = f2b(sc[kt][r]);
        }
    }
    {   // zero the one tile in this wave's PV range not covered by [w, w+8]
        int zkt = (wave & 1) ? (wave - 1) : (wave + 9);
#pragma unroll
        for (int r0 = 0; r0 < 4; ++r0) {
            int r = (r0 + quad) & 3;
            Pb[(quad * 4 + r) * VP + zkt * 16 + lm] = 0;
        }
    }
    __syncthreads();

    // O[16q][64d] = P * V^T over 5 of 6 32-key chunks
    int jclo = wave >> 1;
    f32x4 o[4];
#pragma unroll
    for (int n = 0; n < 4; ++n) o[n] = (f32x4){0.f, 0.f, 0.f, 0.f};
#pragma unroll
    for (int jc2 = 0; jc2 < 5; ++jc2) {
        int jc = jclo + jc2;
        bf16x8 pf = *(const bf16x8*)(Pb + lm * VP + jc * 32 + quad * 8);
#pragma unroll
        for (int n = 0; n < 4; ++n) {
            bf16x8 vf = *(const bf16x8*)(Vt + (n * 16 + lm) * VP + jc * 32 + quad * 8);
            o[n] = __builtin_amdgcn_mfma_f32_16x16x32_bf16(pf, vf, o[n], 0, 0, 0);
        }
    }

    float inv[4];
#pragma unroll
    for (int r = 0; r < 4; ++r) inv[r] = 1.0f / sum[r];
#pragma unroll
    for (int n = 0; n < 4; ++n)
#pragma unroll
        for (int r = 0; r < 4; ++r) {
            int orow = q0 + wave * 16 + quad * 4 + r;
            size_t oidx = ((size_t)(b * 1024 + orow)) * 1024 + h * 64 + n * 16 + lm;
            Og[oidx] = f2b(o[n][r] * inv[r]);
        }
}

// ---- proj GEMM: out[M,N] = attn[M,K] * w2b[N,K]^T + b2, f32 out ----
// Reverted to 128x128 (round-13's 128x64 was +4us: proj is NOT occupancy-
// bound; smaller tile just doubled block-rounds and W re-reads).
__global__ void __launch_bounds__(256) gemm_proj(
    const unsigned short* __restrict__ A,   // attn [8192,1024] bf16
    const unsigned short* __restrict__ W,   // w2b [1024,1024] bf16
    const float* __restrict__ bias,         // [1024] f32
    float* __restrict__ Out)                // [8192,1024] f32
{
    const int K = 1024;
    int n0 = blockIdx.x * BN;
    int m0 = blockIdx.y * BM;
    int tid = threadIdx.x;
    int wave = tid >> 6, lane = tid & 63;
    int lm = lane & 15, quad = lane >> 4;
    int mblk = (wave & 1) * 64, nblk = (wave >> 1) * 64;

    __shared__ unsigned short As[BM * BK];
    __shared__ unsigned short Bs[BN * BK];

    int drow = lane >> 3;
    int gcc  = (lane & 7) ^ drow;
    const unsigned short* ga[4]; const unsigned short* gb[4];
    unsigned short *la[4], *lb[4];
#pragma unroll
    for (int p = 0; p < 4; ++p) {
        int r = wave * 32 + p * 8 + drow;
        ga[p] = A + (size_t)(m0 + r) * K + gcc * 8;
        gb[p] = W + (size_t)(n0 + r) * K + gcc * 8;
        la[p] = As + (wave * 32 + p * 8) * 64;
        lb[p] = Bs + (wave * 32 + p * 8) * 64;
    }
    int lm7 = lm & 7;

    f32x4 acc[4][4];
#pragma unroll
    for (int i = 0; i < 4; ++i)
#pragma unroll
        for (int j = 0; j < 4; ++j)
            acc[i][j] = (f32x4){0.f, 0.f, 0.f, 0.f};

    for (int k0 = 0; k0 < K; k0 += BK) {
        __syncthreads();
#pragma unroll
        for (int p = 0; p < 4; ++p) gld16(ga[p] + k0, la[p]);
#pragma unroll
        for (int p = 0; p < 4; ++p) gld16(gb[p] + k0, lb[p]);
        __syncthreads();
        bf16x8 af[4][2], bfr[4][2];
#pragma unroll
        for (int i = 0; i < 4; ++i)
#pragma unroll
            for (int hhh = 0; hhh < 2; ++hhh)
                af[i][hhh] = *(const bf16x8*)(As + (mblk + i * 16 + lm) * 64 +
                                              (((hhh * 4 + quad) ^ lm7) << 3));
#pragma unroll
        for (int j = 0; j < 4; ++j)
#pragma unroll
            for (int hhh = 0; hhh < 2; ++hhh)
                bfr[j][hhh] = *(const bf16x8*)(Bs + (nblk + j * 16 + lm) * 64 +
                                               (((hhh * 4 + quad) ^ lm7) << 3));
#pragma unroll
        for (int i = 0; i < 4; ++i)
#pragma unroll
            for (int j = 0; j < 4; ++j) {
                acc[i][j] = __builtin_amdgcn_mfma_f32_16x16x32_bf16(af[i][0], bfr[j][0], acc[i][j], 0, 0, 0);
                acc[i][j] = __builtin_amdgcn_mfma_f32_16x16x32_bf16(af[i][1], bfr[j][1], acc[i][j], 0, 0, 0);
            }
    }

#pragma unroll
    for (int j = 0; j < 4; ++j) {
        int n = n0 + nblk + j * 16 + lm;
        float bv = bias[n];
#pragma unroll
        for (int i = 0; i < 4; ++i) {
#pragma unroll
            for (int r = 0; r < 4; ++r) {
                int m = m0 + mblk + i * 16 + quad * 4 + r;
                Out[(size_t)m * 1024 + n] = acc[i][j][r] + bv;
            }
        }
    }
}

extern "C" void kernel_launch(void* const* d_in, const int* in_sizes, int n_in,
                              void* d_out, int out_size, void* d_ws, size_t ws_size,
                              hipStream_t stream) {
    const float* x  = (const float*)d_in[0];  // [8,1024,1024] f32
    const float* w1 = (const float*)d_in[1];  // [3072,1024] f32
    const float* b1 = (const float*)d_in[2];  // [3072] f32
    const float* w2 = (const float*)d_in[3];  // [1024,1024] f32
    const float* b2 = (const float*)d_in[4];  // [1024] f32
    float* out = (float*)d_out;               // [8192,1024] f32

    // ws (56 MiB peak):
    //  [0,16Mi)   xb  -> overlaid by attn after gemm_qkv
    //  [16,22Mi)  w1b -> dead after gemm_qkv
    //  [22,24Mi)  w2b
    //  [24,40Mi)  q   [40,56Mi) k
    //  v lives in d_out's first 16 MiB (dead before gemm_proj writes out)
    char* ws = (char*)d_ws;
    const size_t MB = 1024 * 1024;
    unsigned short* xb   = (unsigned short*)(ws);
    unsigned short* w1b  = (unsigned short*)(ws + 16 * MB);
    unsigned short* w2b  = (unsigned short*)(ws + 22 * MB);
    unsigned short* q    = (unsigned short*)(ws + 24 * MB);
    unsigned short* k    = (unsigned short*)(ws + 40 * MB);
    unsigned short* v    = (unsigned short*)d_out;
    unsigned short* attn = (unsigned short*)(ws);

    dim3 blk(256);
    cast_inputs<<<1536, blk, 0, stream>>>(
        (const float4*)x, (const float4*)w1, (const float4*)w2,
        (uint4*)xb, (uint4*)w1b, (uint4*)w2b);
    // two half-N dispatches (~34us each) so attn/proj surface in top-5
    gemm_qkv<<<dim3(12, 64), blk, 0, stream>>>(xb, w1b, b1, q, k, v, 0);
    gemm_qkv<<<dim3(12, 64), blk, 0, stream>>>(xb, w1b, b1, q, k, v, 1536);
    attn_local<<<dim3(2048), blk, 0, stream>>>(q, k, v, attn);
    gemm_proj<<<dim3(8, 64), blk, 0, stream>>>(attn, w2b, b2, out);
}

// Round 7
// 208.107 us; speedup vs baseline: 1.1311x; 1.1311x over previous
//
#include <hip/hip_runtime.h>
#include <hip/hip_bf16.h>
#include <stdint.h>

// Problem: B=8, L=1024, C=1024, H=16, HD=64, window +/-64 (WS=128).
// Round-16 = round-15 resubmitted verbatim (round-15 hit an infra failure:
// "MI355X container failed twice"; kernel re-audited for fault-safety —
// LDS 76.8KB static OK, all LDS vector accesses 16B-aligned, all index
// ranges in-bounds, coverage math re-verified vs the proven 64-row attn).
//  - qkv split REVERTED (r14: +26us, each half re-fetches full A traffic).
//  - attn: 128 q-rows/block, 8 waves (512 thr), 1024 blocks. Per-wave math
//    IDENTICAL (wave w: 16 q-rows, key tiles [w,w+8], 5 PV chunks, zero
//    tile); 256-key window staged ONCE: K/V traffic 96->64MB, blocks/
//    barriers/Q-setup halved, 16 waves/CU. LDS 76.8KB -> 2 blocks/CU.
//  - ws shrunk 56->40MB: q moved to d_out[16,32) (v already d_out[0,16);
//    both dead before proj writes out).

typedef __attribute__((ext_vector_type(8))) short bf16x8;
typedef __attribute__((ext_vector_type(4))) float f32x4;

__device__ inline unsigned short f2b(float f) {
    __hip_bfloat16 h = __float2bfloat16(f);
    return *reinterpret_cast<unsigned short*>(&h);
}

// async global->LDS, 16B per lane; LDS dest = wave-uniform base + lane*16
__device__ inline void gld16(const unsigned short* g, unsigned short* l) {
    __builtin_amdgcn_global_load_lds(
        (const __attribute__((address_space(1))) void*)g,
        (__attribute__((address_space(3))) void*)l, 16, 0, 0);
}

#define BM 128
#define BN 128
#define BK 64

// ---- cast f32 inputs to bf16 side buffers: 8 f32 -> one 16B store ----
__global__ void __launch_bounds__(256) cast_inputs(
    const float4* __restrict__ x, const float4* __restrict__ w1,
    const float4* __restrict__ w2,
    uint4* __restrict__ xb, uint4* __restrict__ w1b, uint4* __restrict__ w2b)
{
    const int P0 = 1048576, P1 = 393216, P2 = 131072;  // float4-pair counts
    int stride = gridDim.x * blockDim.x;
    for (int i = blockIdx.x * blockDim.x + threadIdx.x; i < P0 + P1 + P2; i += stride) {
        const float4* src; uint4* dst; int idx;
        if (i < P0)           { src = x;  dst = xb;  idx = i; }
        else if (i < P0 + P1) { src = w1; dst = w1b; idx = i - P0; }
        else                  { src = w2; dst = w2b; idx = i - P0 - P1; }
        float4 a = src[idx * 2], b = src[idx * 2 + 1];
        unsigned short t[8] = {f2b(a.x), f2b(a.y), f2b(a.z), f2b(a.w),
                               f2b(b.x), f2b(b.y), f2b(b.z), f2b(b.w)};
        dst[idx] = *(uint4*)t;
    }
}

// ---- QKV GEMM: C[M,N] = xb[M,K] * w1b[N,K]^T + b1 ; scatter to Q/K/V ----
// 128x64 LDS tiles, XOR swizzle (chunk c of row r at c^(r&7)); DMA staging.
__global__ void __launch_bounds__(256) gemm_qkv(
    const unsigned short* __restrict__ A,   // xb [8192,1024] bf16
    const unsigned short* __restrict__ W,   // w1b [3072,1024] bf16
    const float* __restrict__ bias,         // [3072] f32
    unsigned short* __restrict__ Qo,
    unsigned short* __restrict__ Ko,
    unsigned short* __restrict__ Vo)
{
    const int K = 1024;
    int n0 = blockIdx.x * BN;
    int m0 = blockIdx.y * BM;
    int tid = threadIdx.x;
    int wave = tid >> 6, lane = tid & 63;
    int lm = lane & 15, quad = lane >> 4;
    int mblk = (wave & 1) * 64, nblk = (wave >> 1) * 64;

    __shared__ unsigned short As[BM * BK];  // 16 KiB
    __shared__ unsigned short Bs[BN * BK];  // 16 KiB

    int drow = lane >> 3;               // 0..7 row within an 8-row DMA chunk
    int gcc  = (lane & 7) ^ drow;       // swizzled logical col-chunk (x8 elems)
    const unsigned short* ga[4]; const unsigned short* gb[4];
    unsigned short *la[4], *lb[4];
#pragma unroll
    for (int p = 0; p < 4; ++p) {
        int r = wave * 32 + p * 8 + drow;
        ga[p] = A + (size_t)(m0 + r) * K + gcc * 8;
        gb[p] = W + (size_t)(n0 + r) * K + gcc * 8;
        la[p] = As + (wave * 32 + p * 8) * 64;
        lb[p] = Bs + (wave * 32 + p * 8) * 64;
    }
    int lm7 = lm & 7;

    f32x4 acc[4][4];
#pragma unroll
    for (int i = 0; i < 4; ++i)
#pragma unroll
        for (int j = 0; j < 4; ++j)
            acc[i][j] = (f32x4){0.f, 0.f, 0.f, 0.f};

    for (int k0 = 0; k0 < K; k0 += BK) {
        __syncthreads();                 // prev iter's ds_reads done
#pragma unroll
        for (int p = 0; p < 4; ++p) gld16(ga[p] + k0, la[p]);
#pragma unroll
        for (int p = 0; p < 4; ++p) gld16(gb[p] + k0, lb[p]);
        __syncthreads();                 // DMA drained
        bf16x8 af[4][2], bfr[4][2];
#pragma unroll
        for (int i = 0; i < 4; ++i)
#pragma unroll
            for (int hhh = 0; hhh < 2; ++hhh)
                af[i][hhh] = *(const bf16x8*)(As + (mblk + i * 16 + lm) * 64 +
                                              (((hhh * 4 + quad) ^ lm7) << 3));
#pragma unroll
        for (int j = 0; j < 4; ++j)
#pragma unroll
            for (int hhh = 0; hhh < 2; ++hhh)
                bfr[j][hhh] = *(const bf16x8*)(Bs + (nblk + j * 16 + lm) * 64 +
                                               (((hhh * 4 + quad) ^ lm7) << 3));
#pragma unroll
        for (int i = 0; i < 4; ++i)
#pragma unroll
            for (int j = 0; j < 4; ++j) {
                acc[i][j] = __builtin_amdgcn_mfma_f32_16x16x32_bf16(af[i][0], bfr[j][0], acc[i][j], 0, 0, 0);
                acc[i][j] = __builtin_amdgcn_mfma_f32_16x16x32_bf16(af[i][1], bfr[j][1], acc[i][j], 0, 0, 0);
            }
    }

#pragma unroll
    for (int j = 0; j < 4; ++j) {
        int n = n0 + nblk + j * 16 + lm;
        float bv = bias[n];
        int sec = n >> 10, rem = n & 1023;
        int h = rem >> 6, d = rem & 63;
        unsigned short* dst = (sec == 0) ? Qo : (sec == 1) ? Ko : Vo;
#pragma unroll
        for (int i = 0; i < 4; ++i) {
#pragma unroll
            for (int r = 0; r < 4; ++r) {
                int m = m0 + mblk + i * 16 + quad * 4 + r;
                int bb = m >> 10, sl = m & 1023;
                size_t idx = ((size_t)((bb * 16 + h) * 1024 + sl)) * 64 + d;
                dst[idx] = f2b(acc[i][j][r] + bv);
            }
        }
    }
}

// ---- local attention, 128 q-rows/block, 8 waves ----
// One block per (b,h,128-row q tile). Keys window [q0-64, q0+192) = 256.
// Wave w (q rows [q0+16w,+16)) computes key tiles [w, w+8] (9 of 16) and
// 5 of 8 PV chunks; the one uncovered tile in its range is zeroed in P.
// Per-wave math identical to the proven 64-row version.
__global__ void __launch_bounds__(512) attn_local(
    const unsigned short* __restrict__ Qg,   // [B*H,1024,64] bf16
    const unsigned short* __restrict__ Kg,   // [B*H,1024,64] bf16
    const unsigned short* __restrict__ Vg,   // [B*H,1024,64] bf16
    unsigned short* __restrict__ Og)         // [8192,1024] bf16
{
    const int KP = 72;    // K-tile pitch (64+8)
    const int VP = 264;   // Vt pitch (256+8)
    const int PP = 168;   // per-wave P pitch (160+8), relative to jclo*32
    // LDS: Vt [64][264] ; Ks [256][72] ; P overlays Ks (union, 21504 shorts)
    __shared__ unsigned short S[64 * VP + 21504];   // 76.8 KiB
    unsigned short* Vt = S;
    unsigned short* Ks = S + 64 * VP;

    int tid = threadIdx.x;
    int wave = tid >> 6, lane = tid & 63;
    int lm = lane & 15, quad = lane >> 4;

    int bh = blockIdx.x >> 3;
    int qt = blockIdx.x & 7;
    int q0 = qt * 128;
    int b = bh >> 4, h = bh & 15;
    const unsigned short* Qbh = Qg + (size_t)bh * 1024 * 64;
    const unsigned short* Kbh = Kg + (size_t)bh * 1024 * 64;
    const unsigned short* Vbh = Vg + (size_t)bh * 1024 * 64;
    int j0 = q0 - 64;

    // stage K rows + V^T for 256-key window (write order staggered by tid&7)
    int k7 = tid & 7;
#pragma unroll
    for (int it = 0; it < 4; ++it) {
        int id = it * 512 + tid;
        int r = id >> 3;             // key row 0..255
        int c = (id & 7) * 8;        // d offset
        int j = j0 + r;
        uint4 kv, vv;
        kv.x = kv.y = kv.z = kv.w = 0;
        vv = kv;
        if (j >= 0 && j < 1024) {
            kv = *(const uint4*)(Kbh + (size_t)j * 64 + c);
            vv = *(const uint4*)(Vbh + (size_t)j * 64 + c);
        }
        *(uint4*)(Ks + r * KP + c) = kv;
        unsigned short tmp[8];
        *(uint4*)tmp = vv;
#pragma unroll
        for (int e0 = 0; e0 < 8; ++e0) {
            int e = (e0 + k7) & 7;
            Vt[(c + e) * VP + r] = tmp[e];
        }
    }
    __syncthreads();

    int qrow = q0 + wave * 16;
    bf16x8 qf0 = *(const bf16x8*)(Qbh + (size_t)(qrow + lm) * 64 + quad * 8);
    bf16x8 qf1 = *(const bf16x8*)(Qbh + (size_t)(qrow + lm) * 64 + 32 + quad * 8);

    // scores: 9 key tiles [wave, wave+8]
    f32x4 sc[9];
#pragma unroll
    for (int kt = 0; kt < 9; ++kt) {
        int akt = wave + kt;
        f32x4 a = (f32x4){0.f, 0.f, 0.f, 0.f};
        bf16x8 k0f = *(const bf16x8*)(Ks + (akt * 16 + lm) * KP + quad * 8);
        bf16x8 k1f = *(const bf16x8*)(Ks + (akt * 16 + lm) * KP + 32 + quad * 8);
        a = __builtin_amdgcn_mfma_f32_16x16x32_bf16(qf0, k0f, a, 0, 0, 0);
        a = __builtin_amdgcn_mfma_f32_16x16x32_bf16(qf1, k1f, a, 0, 0, 0);
        sc[kt] = a;
    }

    float mx[4] = {-3e38f, -3e38f, -3e38f, -3e38f};
#pragma unroll
    for (int kt = 0; kt < 9; ++kt) {
        int jg = j0 + (wave + kt) * 16 + lm;
#pragma unroll
        for (int r = 0; r < 4; ++r) {
            int irow = q0 + wave * 16 + quad * 4 + r;
            int diff = irow - jg;
            bool ok = (jg >= 0) && (jg < 1024) && (diff <= 64) && (diff >= -64);
            float s = ok ? sc[kt][r] * 0.125f : -30000.0f;
            sc[kt][r] = s;
            mx[r] = fmaxf(mx[r], s);
        }
    }
#pragma unroll
    for (int off = 1; off <= 8; off <<= 1)
#pragma unroll
        for (int r = 0; r < 4; ++r)
            mx[r] = fmaxf(mx[r], __shfl_xor(mx[r], off, 64));

    float sum[4] = {0.f, 0.f, 0.f, 0.f};
#pragma unroll
    for (int kt = 0; kt < 9; ++kt)
#pragma unroll
        for (int r = 0; r < 4; ++r) {
            float p = __expf(sc[kt][r] - mx[r]);
            sc[kt][r] = p;
            sum[r] += p;
        }
#pragma unroll
    for (int off = 1; off <= 8; off <<= 1)
#pragma unroll
        for (int r = 0; r < 4; ++r)
            sum[r] += __shfl_xor(sum[r], off, 64);

    __syncthreads();  // done reading Ks as K tile
    int jclo = wave >> 1;
    unsigned short* Pb = Ks + wave * 16 * PP;  // per-wave P [16][PP], rel jclo*32
#pragma unroll
    for (int kt = 0; kt < 9; ++kt) {
        int rel = (wave + kt) * 16 - jclo * 32;   // 0..144 (even w) / 16..144 (odd)
#pragma unroll
        for (int r0 = 0; r0 < 4; ++r0) {
            int r = (r0 + quad) & 3;
            Pb[(quad * 4 + r) * PP + rel + lm] = f2b(sc[kt][r]);
        }
    }
    {   // zero the one tile in this wave's PV range not covered by [w, w+8]
        int zkt = (wave & 1) ? (wave - 1) : (wave + 9);
        int rel = zkt * 16 - jclo * 32;
#pragma unroll
        for (int r0 = 0; r0 < 4; ++r0) {
            int r = (r0 + quad) & 3;
            Pb[(quad * 4 + r) * PP + rel + lm] = 0;
        }
    }
    __syncthreads();

    // O[16q][64d] = P * V^T over 5 of 8 32-key chunks
    f32x4 o[4];
#pragma unroll
    for (int n = 0; n < 4; ++n) o[n] = (f32x4){0.f, 0.f, 0.f, 0.f};
#pragma unroll
    for (int jc2 = 0; jc2 < 5; ++jc2) {
        int jc = jclo + jc2;
        bf16x8 pf = *(const bf16x8*)(Pb + lm * PP + jc2 * 32 + quad * 8);
#pragma unroll
        for (int n = 0; n < 4; ++n) {
            bf16x8 vf = *(const bf16x8*)(Vt + (n * 16 + lm) * VP + jc * 32 + quad * 8);
            o[n] = __builtin_amdgcn_mfma_f32_16x16x32_bf16(pf, vf, o[n], 0, 0, 0);
        }
    }

    float inv[4];
#pragma unroll
    for (int r = 0; r < 4; ++r) inv[r] = 1.0f / sum[r];
#pragma unroll
    for (int n = 0; n < 4; ++n)
#pragma unroll
        for (int r = 0; r < 4; ++r) {
            int orow = q0 + wave * 16 + quad * 4 + r;
            size_t oidx = ((size_t)(b * 1024 + orow)) * 1024 + h * 64 + n * 16 + lm;
            Og[oidx] = f2b(o[n][r] * inv[r]);
        }
}

// ---- proj GEMM: out[M,N] = attn[M,K] * w2b[N,K]^T + b2, f32 out ----
__global__ void __launch_bounds__(256) gemm_proj(
    const unsigned short* __restrict__ A,   // attn [8192,1024] bf16
    const unsigned short* __restrict__ W,   // w2b [1024,1024] bf16
    const float* __restrict__ bias,         // [1024] f32
    float* __restrict__ Out)                // [8192,1024] f32
{
    const int K = 1024;
    int n0 = blockIdx.x * BN;
    int m0 = blockIdx.y * BM;
    int tid = threadIdx.x;
    int wave = tid >> 6, lane = tid & 63;
    int lm = lane & 15, quad = lane >> 4;
    int mblk = (wave & 1) * 64, nblk = (wave >> 1) * 64;

    __shared__ unsigned short As[BM * BK];
    __shared__ unsigned short Bs[BN * BK];

    int drow = lane >> 3;
    int gcc  = (lane & 7) ^ drow;
    const unsigned short* ga[4]; const unsigned short* gb[4];
    unsigned short *la[4], *lb[4];
#pragma unroll
    for (int p = 0; p < 4; ++p) {
        int r = wave * 32 + p * 8 + drow;
        ga[p] = A + (size_t)(m0 + r) * K + gcc * 8;
        gb[p] = W + (size_t)(n0 + r) * K + gcc * 8;
        la[p] = As + (wave * 32 + p * 8) * 64;
        lb[p] = Bs + (wave * 32 + p * 8) * 64;
    }
    int lm7 = lm & 7;

    f32x4 acc[4][4];
#pragma unroll
    for (int i = 0; i < 4; ++i)
#pragma unroll
        for (int j = 0; j < 4; ++j)
            acc[i][j] = (f32x4){0.f, 0.f, 0.f, 0.f};

    for (int k0 = 0; k0 < K; k0 += BK) {
        __syncthreads();
#pragma unroll
        for (int p = 0; p < 4; ++p) gld16(ga[p] + k0, la[p]);
#pragma unroll
        for (int p = 0; p < 4; ++p) gld16(gb[p] + k0, lb[p]);
        __syncthreads();
        bf16x8 af[4][2], bfr[4][2];
#pragma unroll
        for (int i = 0; i < 4; ++i)
#pragma unroll
            for (int hhh = 0; hhh < 2; ++hhh)
                af[i][hhh] = *(const bf16x8*)(As + (mblk + i * 16 + lm) * 64 +
                                              (((hhh * 4 + quad) ^ lm7) << 3));
#pragma unroll
        for (int j = 0; j < 4; ++j)
#pragma unroll
            for (int hhh = 0; hhh < 2; ++hhh)
                bfr[j][hhh] = *(const bf16x8*)(Bs + (nblk + j * 16 + lm) * 64 +
                                               (((hhh * 4 + quad) ^ lm7) << 3));
#pragma unroll
        for (int i = 0; i < 4; ++i)
#pragma unroll
            for (int j = 0; j < 4; ++j) {
                acc[i][j] = __builtin_amdgcn_mfma_f32_16x16x32_bf16(af[i][0], bfr[j][0], acc[i][j], 0, 0, 0);
                acc[i][j] = __builtin_amdgcn_mfma_f32_16x16x32_bf16(af[i][1], bfr[j][1], acc[i][j], 0, 0, 0);
            }
    }

#pragma unroll
    for (int j = 0; j < 4; ++j) {
        int n = n0 + nblk + j * 16 + lm;
        float bv = bias[n];
#pragma unroll
        for (int i = 0; i < 4; ++i) {
#pragma unroll
            for (int r = 0; r < 4; ++r) {
                int m = m0 + mblk + i * 16 + quad * 4 + r;
                Out[(size_t)m * 1024 + n] = acc[i][j][r] + bv;
            }
        }
    }
}

extern "C" void kernel_launch(void* const* d_in, const int* in_sizes, int n_in,
                              void* d_out, int out_size, void* d_ws, size_t ws_size,
                              hipStream_t stream) {
    const float* x  = (const float*)d_in[0];  // [8,1024,1024] f32
    const float* w1 = (const float*)d_in[1];  // [3072,1024] f32
    const float* b1 = (const float*)d_in[2];  // [3072] f32
    const float* w2 = (const float*)d_in[3];  // [1024,1024] f32
    const float* b2 = (const float*)d_in[4];  // [1024] f32
    float* out = (float*)d_out;               // [8192,1024] f32

    // ws (40 MiB peak):
    //  [0,16Mi)   xb  -> overlaid by attn output after gemm_qkv
    //  [16,22Mi)  w1b -> dead after gemm_qkv
    //  [22,24Mi)  w2b
    //  [24,40Mi)  k
    //  v = d_out[0,16Mi), q = d_out[16,32Mi) — both dead before proj writes
    char* ws = (char*)d_ws;
    const size_t MB = 1024 * 1024;
    unsigned short* xb   = (unsigned short*)(ws);
    unsigned short* w1b  = (unsigned short*)(ws + 16 * MB);
    unsigned short* w2b  = (unsigned short*)(ws + 22 * MB);
    unsigned short* k    = (unsigned short*)(ws + 24 * MB);
    unsigned short* v    = (unsigned short*)d_out;
    unsigned short* q    = (unsigned short*)((char*)d_out + 16 * MB);
    unsigned short* attn = (unsigned short*)(ws);

    dim3 blk(256);
    cast_inputs<<<1536, blk, 0, stream>>>(
        (const float4*)x, (const float4*)w1, (const float4*)w2,
        (uint4*)xb, (uint4*)w1b, (uint4*)w2b);
    gemm_qkv<<<dim3(24, 64), blk, 0, stream>>>(xb, w1b, b1, q, k, v);
    attn_local<<<dim3(1024), dim3(512), 0, stream>>>(q, k, v, attn);
    gemm_proj<<<dim3(8, 64), blk, 0, stream>>>(attn, w2b, b2, out);
}